// Round 8
// baseline (130.526 us; speedup 1.0000x reference)
//
#include <hip/hip_runtime.h>
#include <math.h>

#define H    64
#define N    256
#define D    128
#define L    16
#define SEG4   112                 // float4 per 448-col segment
#define F3IN (N * 448)             // 114688 floats per W1 row
#define CG4   1792                 // float4 per column group (16 segments)

typedef float v4f __attribute__((ext_vector_type(4)));

__device__ __forceinline__ float sigmoidf_(float x) {
    return 1.0f / (1.0f + expf(-x));
}
__device__ __forceinline__ float dot4(float4 a, float4 b) {
    return a.x * b.x + a.y * b.y + a.z * b.z + a.w * b.w;
}
__device__ __forceinline__ float dotv(v4f a, v4f b) {
    return a[0] * b[0] + a[1] * b[1] + a[2] * b[2] + a[3] * b[3];
}

// ---------------------------------------------------------------------------
// Mega kernel: EVERY block redundantly computes the encoder (emb gather +
// GRU + f1W transform + factored flat softmax; Z_ij = u_i + v_j + const,
// const cancels) into LDS — bit-identical across blocks, so deterministic —
// then streams its W1 chunk (16 rows x 1 column-group) against the virtual x.
// No inter-block dependency, no atomics, no fences, no grid sync.
// 512 blocks x 256 threads, 2 blocks/CU, all resident at once.
// ---------------------------------------------------------------------------
__global__ __launch_bounds__(256, 2) void k_mega(
    const int* __restrict__ token_ids, const float* __restrict__ emb_table,
    const float* __restrict__ Wih, const float* __restrict__ Whh,
    const float* __restrict__ bih, const float* __restrict__ bhh,
    const float* __restrict__ f1W, const float* __restrict__ obs,
    const float* __restrict__ W1, float* __restrict__ partial)
{
    __shared__ float emb_s[L * H];      // 4 KB
    __shared__ float gi_all[L * 192];   // 12 KB
    __shared__ float h_s[H];
    __shared__ float gh_s[192];
    __shared__ float wa_s[D];
    __shared__ float wb_s[D];
    __shared__ float eus_s[N];
    __shared__ float ev_s[N];
    __shared__ float wred[4][4];
    __shared__ float red[16][4];

    const int k = threadIdx.x;
    const int wave = k >> 6, lane = k & 63;

    // ---------------- encoder (redundant per block) ----------------
    {
        int tok = token_ids[k >> 4];
        ((float4*)emb_s)[k] = ((const float4*)emb_table)[tok * 16 + (k & 15)];
    }
    if (k < H) h_s[k] = 0.0f;

    // Whh gate row in registers (64 VGPR); Wih streamed from cache in hoist
    float4 whh4[16];
    float bi = 0.0f, bh = 0.0f;
    if (k < 192) {
        const float4* wh = (const float4*)(Whh + k * H);
#pragma unroll
        for (int c = 0; c < 16; ++c) whh4[c] = wh[c];
        bi = bih[k]; bh = bhh[k];
    }

    // f1W column k preloaded (consumed after GRU; latency hidden)
    float f1wreg[64];
#pragma unroll
    for (int kk = 0; kk < 64; ++kk) f1wreg[kk] = f1W[kk * 256 + k];

    __syncthreads();

    // hoist input-gate terms: gi_all[t][k] = bih[k] + Wih[k,:].emb[t]
    if (k < 192) {
        float gi[L];
#pragma unroll
        for (int tt = 0; tt < L; ++tt) gi[tt] = bi;
        const float4* wi = (const float4*)(Wih + k * H);
#pragma unroll
        for (int c = 0; c < 16; ++c) {
            float4 w = wi[c];
#pragma unroll
            for (int tt = 0; tt < L; ++tt)
                gi[tt] += dot4(w, ((const float4*)(emb_s + tt * 64))[c]);
        }
#pragma unroll
        for (int tt = 0; tt < L; ++tt) gi_all[tt * 192 + k] = gi[tt];
    }
    __syncthreads();

    // serial GRU, 2 barriers per step
    for (int tt = 0; tt < L; ++tt) {
        if (k < 192) {
            const float4* hv = (const float4*)h_s;
            float a0 = 0, a1 = 0, a2 = 0, a3 = 0;
#pragma unroll
            for (int c = 0; c < 16; c += 4) {
                a0 += dot4(whh4[c],     hv[c]);
                a1 += dot4(whh4[c + 1], hv[c + 1]);
                a2 += dot4(whh4[c + 2], hv[c + 2]);
                a3 += dot4(whh4[c + 3], hv[c + 3]);
            }
            gh_s[k] = (a0 + a1) + (a2 + a3) + bh;
        }
        __syncthreads();
        if (k < H) {
            float r = sigmoidf_(gi_all[tt * 192 + k] + gh_s[k]);
            float z = sigmoidf_(gi_all[tt * 192 + 64 + k] + gh_s[64 + k]);
            float n = tanhf(gi_all[tt * 192 + 128 + k] + r * gh_s[128 + k]);
            h_s[k] = (1.0f - z) * n + z * h_s[k];
        }
        __syncthreads();
    }

    // wa = f1W[:, :128]^T g ; wb = f1W[:, 128:]^T g
    {
        float s = 0.0f;
#pragma unroll
        for (int kk = 0; kk < 64; ++kk) s += f1wreg[kk] * h_s[kk];
        if (k < D) wa_s[k] = s;
        else       wb_s[k - D] = s;
    }
    __syncthreads();

    // u_i, v_i (thread = row i)
    float4 orow[32];
    {
        const float4* rp = (const float4*)(obs + k * D);
#pragma unroll
        for (int c = 0; c < 32; ++c) orow[c] = rp[c];
    }
    float u = 0.0f, v = 0.0f;
#pragma unroll
    for (int c = 0; c < 32; ++c) {
        u += dot4(orow[c], ((const float4*)wa_s)[c]);
        v += dot4(orow[c], ((const float4*)wb_s)[c]);
    }

    // wave-shuffle reductions, 2 barriers total
    float um = u, vm = v;
#pragma unroll
    for (int off = 32; off > 0; off >>= 1) {
        um = fmaxf(um, __shfl_xor(um, off, 64));
        vm = fmaxf(vm, __shfl_xor(vm, off, 64));
    }
    if (lane == 0) { wred[0][wave] = um; wred[1][wave] = vm; }
    __syncthreads();
    const float mu = fmaxf(fmaxf(wred[0][0], wred[0][1]), fmaxf(wred[0][2], wred[0][3]));
    const float mv = fmaxf(fmaxf(wred[1][0], wred[1][1]), fmaxf(wred[1][2], wred[1][3]));

    const float eui = expf(u - mu), evi = expf(v - mv);
    float us = eui, vs = evi;
#pragma unroll
    for (int off = 32; off > 0; off >>= 1) {
        us += __shfl_xor(us, off, 64);
        vs += __shfl_xor(vs, off, 64);
    }
    if (lane == 0) { wred[2][wave] = us; wred[3][wave] = vs; }
    __syncthreads();
    const float Su = (wred[2][0] + wred[2][1]) + (wred[2][2] + wred[2][3]);
    const float Sv = (wred[3][0] + wred[3][1]) + (wred[3][2] + wred[3][3]);

    eus_s[k] = eui * (1.0f / (Su * Sv));
    ev_s[k]  = evi;
    __syncthreads();

    // ---------------- W1 stream: 16 rows x column-group cg ----------------
    const int cg   = blockIdx.x & 15;
    const int rgrp = blockIdx.x >> 4;      // 0..31 -> rows rgrp*16 .. +15

    // virtual-x slice for this column group (from LDS; built once)
    v4f xr[7];
    {
        const float4* obs4 = (const float4*)obs;
#pragma unroll
        for (int j = 0; j < 7; ++j) {
            int idx = wave * 448 + j * 64 + lane;   // < 1792
            int s   = idx / SEG4;
            int c   = idx - s * SEG4;
            int seg = cg * 16 + s;
            float4 o;
            if (c < 32)       o = obs4[seg * 32 + c];
            else if (c < 48)  o = ((const float4*)h_s)[c - 32];
            else {
                float4 e = ((const float4*)ev_s)[c - 48];
                float m = eus_s[seg];
                o = make_float4(e.x * m, e.y * m, e.z * m, e.w * m);
            }
            xr[j] = (v4f){o.x, o.y, o.z, o.w};
        }
    }

    // stream 16 rows (pairs -> 14 loads in flight), each wave 7 KB/row
    const v4f* w0 = (const v4f*)W1 + (size_t)(rgrp * 16) * (F3IN / 4)
                  + (size_t)cg * CG4 + wave * 448 + lane;
    float sums[16];
#pragma unroll
    for (int rp = 0; rp < 8; ++rp) {
        const v4f* wra = w0 + (size_t)(2 * rp) * (F3IN / 4);
        const v4f* wrb = wra + (F3IN / 4);
        float s0a = 0, s0b = 0, s1a = 0, s1b = 0;
#pragma unroll
        for (int j = 0; j < 7; ++j) {
            v4f wa = wra[j * 64];
            v4f wb = wrb[j * 64];
            float da = dotv(wa, xr[j]);
            float db = dotv(wb, xr[j]);
            if (j & 1) { s0b += da; s1b += db; }
            else       { s0a += da; s1a += db; }
        }
        sums[2 * rp]     = s0a + s0b;
        sums[2 * rp + 1] = s1a + s1b;
    }

    __syncthreads();   // reuse red[][]
#pragma unroll
    for (int rr = 0; rr < 16; ++rr) {
        float s = sums[rr];
#pragma unroll
        for (int off = 32; off > 0; off >>= 1) s += __shfl_down(s, off, 64);
        if (lane == 0) red[rr][wave] = s;
    }
    __syncthreads();
    if (k < 16)
        partial[(rgrp * 16 + k) * 16 + cg] =
            red[k][0] + red[k][1] + red[k][2] + red[k][3];
}

// ---------------------------------------------------------------------------
// Finish: h1 = relu(sum of 16 partials + b1); out = W2 @ h1 + b2. One block.
// ---------------------------------------------------------------------------
__global__ __launch_bounds__(512) void k_finish(
    const float* __restrict__ partial, const float* __restrict__ b1,
    const float* __restrict__ W2, const float* __restrict__ b2,
    float* __restrict__ out)
{
    __shared__ float h1s[512];
    const int r = threadIdx.x;
    {
        const float4* p4 = (const float4*)(partial + r * 16);
        float4 A = p4[0], B = p4[1], C = p4[2], E = p4[3];
        float s = (A.x + A.y + A.z + A.w) + (B.x + B.y + B.z + B.w)
                + (C.x + C.y + C.z + C.w) + (E.x + E.y + E.z + E.w);
        h1s[r] = fmaxf(s + b1[r], 0.0f);
    }
    __syncthreads();

    const int wave = r >> 6, lane = r & 63;
    for (int row = wave; row < 40; row += 8) {
        float s = 0.0f;
#pragma unroll
        for (int c = 0; c < 8; ++c)
            s += W2[row * 512 + lane + c * 64] * h1s[lane + c * 64];
#pragma unroll
        for (int off = 32; off > 0; off >>= 1) s += __shfl_down(s, off, 64);
        if (lane == 0) out[row] = s + b2[row];
    }
}

// ---------------------------------------------------------------------------
extern "C" void kernel_launch(void* const* d_in, const int* in_sizes, int n_in,
                              void* d_out, int out_size, void* d_ws, size_t ws_size,
                              hipStream_t stream)
{
    const float* obs       = (const float*)d_in[0];
    const int*   token_ids = (const int*)  d_in[1];
    const float* emb_table = (const float*)d_in[2];
    const float* Wih       = (const float*)d_in[3];
    const float* Whh       = (const float*)d_in[4];
    const float* bih       = (const float*)d_in[5];
    const float* bhh       = (const float*)d_in[6];
    const float* f1W       = (const float*)d_in[7];
    // d_in[8] = f1_b : cancels in the flat softmax (Z_ij = u_i + v_j + const)
    const float* W1        = (const float*)d_in[9];
    const float* b1        = (const float*)d_in[10];
    const float* W2        = (const float*)d_in[11];
    const float* b2        = (const float*)d_in[12];

    float* ws      = (float*)d_ws;
    float* partial = ws;            // 512*16 = 8192 floats
    float* out     = (float*)d_out;

    k_mega<<<512, 256, 0, stream>>>(token_ids, emb_table, Wih, Whh, bih, bhh,
                                    f1W, obs, W1, partial);
    k_finish<<<1, 512, 0, stream>>>(partial, b1, W2, b2, out);
}

// Round 9
// 120.431 us; speedup vs baseline: 1.0838x; 1.0838x over previous
//
#include <hip/hip_runtime.h>
#include <math.h>

#define H    64
#define N    256
#define D    128
#define L    16
#define SEG4   112                 // float4 per 448-col segment
#define F3IN (N * 448)             // 114688 floats per W1 row
#define CG4   1792                 // float4 per column group (16 segments)

typedef float v4f __attribute__((ext_vector_type(4)));

__device__ __forceinline__ float sigmoidf_(float x) {
    return 1.0f / (1.0f + expf(-x));
}
__device__ __forceinline__ float dot4(float4 a, float4 b) {
    return a.x * b.x + a.y * b.y + a.z * b.z + a.w * b.w;
}
__device__ __forceinline__ float dotv(v4f a, v4f b) {
    return a[0] * b[0] + a[1] * b[1] + a[2] * b[2] + a[3] * b[3];
}

// ---------------------------------------------------------------------------
// Kernel 1: encoder (identical to round 6 / 71.9us baseline).
// PROBE NOTE: launched 3x this round to measure enc time by differencing;
// outputs are bit-identical each launch (deterministic).
// ---------------------------------------------------------------------------
__global__ __launch_bounds__(256, 1) void k_enc(
    const int* __restrict__ token_ids, const float* __restrict__ emb_table,
    const float* __restrict__ Wih, const float* __restrict__ Whh,
    const float* __restrict__ bih, const float* __restrict__ bhh,
    const float* __restrict__ f1W, const float* __restrict__ obs,
    float* __restrict__ g_out, float* __restrict__ eus_out,
    float* __restrict__ ev_out)
{
    __shared__ float emb_s[L * H];
    __shared__ float gi_all[L * 192];
    __shared__ float h_s[H];
    __shared__ float gh_s[192];
    __shared__ float wa_s[D];
    __shared__ float wb_s[D];
    __shared__ float wred[4][4];

    const int k = threadIdx.x;
    const int wave = k >> 6, lane = k & 63;

    {
        int tok = token_ids[k >> 4];
        ((float4*)emb_s)[k] = ((const float4*)emb_table)[tok * 16 + (k & 15)];
    }
    if (k < H) h_s[k] = 0.0f;

    float4 wih4[16], whh4[16];
    float bi = 0.0f, bh = 0.0f;
    if (k < 192) {
        const float4* wi = (const float4*)(Wih + k * H);
        const float4* wh = (const float4*)(Whh + k * H);
#pragma unroll
        for (int c = 0; c < 16; ++c) { wih4[c] = wi[c]; whh4[c] = wh[c]; }
        bi = bih[k]; bh = bhh[k];
    }

    float f1wreg[64];
#pragma unroll
    for (int kk = 0; kk < 64; ++kk) f1wreg[kk] = f1W[kk * 256 + k];

    __syncthreads();

    if (k < 192) {
        float gi[L];
#pragma unroll
        for (int tt = 0; tt < L; ++tt) gi[tt] = bi;
#pragma unroll
        for (int c = 0; c < 16; ++c) {
            float4 w = wih4[c];
#pragma unroll
            for (int tt = 0; tt < L; ++tt)
                gi[tt] += dot4(w, ((const float4*)(emb_s + tt * 64))[c]);
        }
#pragma unroll
        for (int tt = 0; tt < L; ++tt) gi_all[tt * 192 + k] = gi[tt];
    }
    __syncthreads();

    for (int tt = 0; tt < L; ++tt) {
        if (k < 192) {
            const float4* hv = (const float4*)h_s;
            float a0 = 0, a1 = 0, a2 = 0, a3 = 0;
#pragma unroll
            for (int c = 0; c < 16; c += 4) {
                a0 += dot4(whh4[c],     hv[c]);
                a1 += dot4(whh4[c + 1], hv[c + 1]);
                a2 += dot4(whh4[c + 2], hv[c + 2]);
                a3 += dot4(whh4[c + 3], hv[c + 3]);
            }
            gh_s[k] = (a0 + a1) + (a2 + a3) + bh;
        }
        __syncthreads();
        if (k < H) {
            float r = sigmoidf_(gi_all[tt * 192 + k] + gh_s[k]);
            float z = sigmoidf_(gi_all[tt * 192 + 64 + k] + gh_s[64 + k]);
            float n = tanhf(gi_all[tt * 192 + 128 + k] + r * gh_s[128 + k]);
            h_s[k] = (1.0f - z) * n + z * h_s[k];
        }
        __syncthreads();
    }

    {
        float s = 0.0f;
#pragma unroll
        for (int kk = 0; kk < 64; ++kk) s += f1wreg[kk] * h_s[kk];
        if (k < D) wa_s[k] = s;
        else       wb_s[k - D] = s;
        if (k < H) g_out[k] = h_s[k];
    }
    __syncthreads();

    float4 orow[32];
    {
        const float4* rp = (const float4*)(obs + k * D);
#pragma unroll
        for (int c = 0; c < 32; ++c) orow[c] = rp[c];
    }
    float u = 0.0f, v = 0.0f;
#pragma unroll
    for (int c = 0; c < 32; ++c) {
        u += dot4(orow[c], ((const float4*)wa_s)[c]);
        v += dot4(orow[c], ((const float4*)wb_s)[c]);
    }

    float um = u, vm = v;
#pragma unroll
    for (int off = 32; off > 0; off >>= 1) {
        um = fmaxf(um, __shfl_xor(um, off, 64));
        vm = fmaxf(vm, __shfl_xor(vm, off, 64));
    }
    if (lane == 0) { wred[0][wave] = um; wred[1][wave] = vm; }
    __syncthreads();
    const float mu = fmaxf(fmaxf(wred[0][0], wred[0][1]), fmaxf(wred[0][2], wred[0][3]));
    const float mv = fmaxf(fmaxf(wred[1][0], wred[1][1]), fmaxf(wred[1][2], wred[1][3]));

    const float eui = expf(u - mu), evi = expf(v - mv);
    float us = eui, vs = evi;
#pragma unroll
    for (int off = 32; off > 0; off >>= 1) {
        us += __shfl_xor(us, off, 64);
        vs += __shfl_xor(vs, off, 64);
    }
    if (lane == 0) { wred[2][wave] = us; wred[3][wave] = vs; }
    __syncthreads();
    const float Su = (wred[2][0] + wred[2][1]) + (wred[2][2] + wred[2][3]);
    const float Sv = (wred[3][0] + wred[3][1]) + (wred[3][2] + wred[3][3]);

    eus_out[k] = eui * (1.0f / (Su * Sv));
    ev_out[k]  = evi;
}

// ---------------------------------------------------------------------------
// Kernel 2: W1 matvec with virtual x (identical to round 6 / 71.9us baseline).
// ---------------------------------------------------------------------------
__global__ __launch_bounds__(256, 4) void k_mv(
    const float* __restrict__ W1, const float* __restrict__ obs,
    const float* __restrict__ g, const float* __restrict__ eus,
    const float* __restrict__ ev, float* __restrict__ partial)
{
    const int t  = threadIdx.x;
    const int cg = blockIdx.x & 15;
    const int rg = blockIdx.x >> 4;        // 0..255

    v4f xr[7];
    {
        const float4* obs4 = (const float4*)obs;
        const float4* g4   = (const float4*)g;
        const float4* ev4  = (const float4*)ev;
#pragma unroll
        for (int j = 0; j < 7; ++j) {
            int idx = t + j * 256;           // < 1792
            int s   = idx / SEG4;
            int c   = idx - s * SEG4;
            int seg = cg * 16 + s;
            float4 o;
            if (c < 32)       o = obs4[seg * 32 + c];
            else if (c < 48)  o = g4[c - 32];
            else {
                float4 e = ev4[c - 48];
                float m = eus[seg];
                o = make_float4(e.x * m, e.y * m, e.z * m, e.w * m);
            }
            xr[j] = (v4f){o.x, o.y, o.z, o.w};
        }
    }

    const v4f* w0 = (const v4f*)W1 + (size_t)(rg * 2) * (F3IN / 4)
                  + (size_t)cg * CG4 + t;
    const v4f* w1 = w0 + (F3IN / 4);

    float s0a = 0.0f, s0b = 0.0f, s1a = 0.0f, s1b = 0.0f;
#pragma unroll
    for (int j = 0; j < 7; ++j) {
        v4f wa = __builtin_nontemporal_load(w0 + j * 256);
        v4f wb = __builtin_nontemporal_load(w1 + j * 256);
        float da = dotv(wa, xr[j]);
        float db = dotv(wb, xr[j]);
        if (j & 1) { s0b += da; s1b += db; }
        else       { s0a += da; s1a += db; }
    }
    float sums[2] = { s0a + s0b, s1a + s1b };

    __shared__ float red[2][4];
    const int wave = t >> 6, lane = t & 63;
#pragma unroll
    for (int rr = 0; rr < 2; ++rr) {
        float s = sums[rr];
#pragma unroll
        for (int off = 32; off > 0; off >>= 1) s += __shfl_down(s, off, 64);
        if (lane == 0) red[rr][wave] = s;
    }
    __syncthreads();
    if (t < 2)
        partial[(rg * 2 + t) * 16 + cg] =
            red[t][0] + red[t][1] + red[t][2] + red[t][3];
}

// ---------------------------------------------------------------------------
// Kernel 3: finish (identical to round 6).
// ---------------------------------------------------------------------------
__global__ __launch_bounds__(512) void k_finish(
    const float* __restrict__ partial, const float* __restrict__ b1,
    const float* __restrict__ W2, const float* __restrict__ b2,
    float* __restrict__ out)
{
    __shared__ float h1s[512];
    const int r = threadIdx.x;
    {
        const float4* p4 = (const float4*)(partial + r * 16);
        float4 A = p4[0], B = p4[1], C = p4[2], E = p4[3];
        float s = (A.x + A.y + A.z + A.w) + (B.x + B.y + B.z + B.w)
                + (C.x + C.y + C.z + C.w) + (E.x + E.y + E.z + E.w);
        h1s[r] = fmaxf(s + b1[r], 0.0f);
    }
    __syncthreads();

    const int wave = r >> 6, lane = r & 63;
    for (int row = wave; row < 40; row += 8) {
        float s = 0.0f;
#pragma unroll
        for (int c = 0; c < 8; ++c)
            s += W2[row * 512 + lane + c * 64] * h1s[lane + c * 64];
#pragma unroll
        for (int off = 32; off > 0; off >>= 1) s += __shfl_down(s, off, 64);
        if (lane == 0) out[row] = s + b2[row];
    }
}

// ---------------------------------------------------------------------------
extern "C" void kernel_launch(void* const* d_in, const int* in_sizes, int n_in,
                              void* d_out, int out_size, void* d_ws, size_t ws_size,
                              hipStream_t stream)
{
    const float* obs       = (const float*)d_in[0];
    const int*   token_ids = (const int*)  d_in[1];
    const float* emb_table = (const float*)d_in[2];
    const float* Wih       = (const float*)d_in[3];
    const float* Whh       = (const float*)d_in[4];
    const float* bih       = (const float*)d_in[5];
    const float* bhh       = (const float*)d_in[6];
    const float* f1W       = (const float*)d_in[7];
    // d_in[8] = f1_b : cancels in the flat softmax (Z_ij = u_i + v_j + const)
    const float* W1        = (const float*)d_in[9];
    const float* b1        = (const float*)d_in[10];
    const float* W2        = (const float*)d_in[11];
    const float* b2        = (const float*)d_in[12];

    float* ws      = (float*)d_ws;
    float* g       = ws;            // 64
    float* eus     = ws + 64;       // 256
    float* ev      = ws + 320;      // 256
    float* partial = ws + 640;      // 512*16 = 8192
    float* out     = (float*)d_out;

    // PROBE: k_enc launched 3x (identical outputs). enc_time ~=
    // (total - 71.9 - 2*gap) / 2. Next round reverts to a single launch.
    k_enc<<<1, 256, 0, stream>>>(token_ids, emb_table, Wih, Whh, bih, bhh,
                                 f1W, obs, g, eus, ev);
    k_enc<<<1, 256, 0, stream>>>(token_ids, emb_table, Wih, Whh, bih, bhh,
                                 f1W, obs, g, eus, ev);
    k_enc<<<1, 256, 0, stream>>>(token_ids, emb_table, Wih, Whh, bih, bhh,
                                 f1W, obs, g, eus, ev);
    k_mv<<<4096, 256, 0, stream>>>(W1, obs, g, eus, ev, partial);
    k_finish<<<1, 512, 0, stream>>>(partial, b1, W2, b2, out);
}

// Round 10
// 86.453 us; speedup vs baseline: 1.5098x; 1.3930x over previous
//
#include <hip/hip_runtime.h>
#include <math.h>

#define H    64
#define N    256
#define D    128
#define L    16
#define SEG4   112                 // float4 per 448-col segment
#define F3IN (N * 448)             // 114688 floats per W1 row
#define CG4   1792                 // float4 per column group (16 segments)

typedef float v4f __attribute__((ext_vector_type(4)));

__device__ __forceinline__ float sigmoidf_(float x) {
    return 1.0f / (1.0f + expf(-x));
}
__device__ __forceinline__ float dot4(float4 a, float4 b) {
    return a.x * b.x + a.y * b.y + a.z * b.z + a.w * b.w;
}
__device__ __forceinline__ float dotv(v4f a, v4f b) {
    return a[0] * b[0] + a[1] * b[1] + a[2] * b[2] + a[3] * b[3];
}

// ---------------------------------------------------------------------------
// Kernel 1: GRU ONLY (serial part). 1 block, 256 threads. Cold reads cut to
// ~100 KB (emb gather + Wih + Whh). Writes g[64].
// ---------------------------------------------------------------------------
__global__ __launch_bounds__(256, 1) void k_gru(
    const int* __restrict__ token_ids, const float* __restrict__ emb_table,
    const float* __restrict__ Wih, const float* __restrict__ Whh,
    const float* __restrict__ bih, const float* __restrict__ bhh,
    float* __restrict__ g_out)
{
    __shared__ float emb_s[L * H];
    __shared__ float gi_all[L * 192];
    __shared__ float h_s[H];
    __shared__ float gh_s[192];

    const int k = threadIdx.x;

    {
        int tok = token_ids[k >> 4];
        ((float4*)emb_s)[k] = ((const float4*)emb_table)[tok * 16 + (k & 15)];
    }
    if (k < H) h_s[k] = 0.0f;

    float4 wih4[16], whh4[16];
    float bi = 0.0f, bh = 0.0f;
    if (k < 192) {
        const float4* wi = (const float4*)(Wih + k * H);
        const float4* wh = (const float4*)(Whh + k * H);
#pragma unroll
        for (int c = 0; c < 16; ++c) { wih4[c] = wi[c]; whh4[c] = wh[c]; }
        bi = bih[k]; bh = bhh[k];
    }
    __syncthreads();

    // hoist input-gate terms: gi_all[t][k] = bih[k] + Wih[k,:].emb[t]
    if (k < 192) {
        float gi[L];
#pragma unroll
        for (int tt = 0; tt < L; ++tt) gi[tt] = bi;
#pragma unroll
        for (int c = 0; c < 16; ++c) {
            float4 w = wih4[c];
#pragma unroll
            for (int tt = 0; tt < L; ++tt)
                gi[tt] += dot4(w, ((const float4*)(emb_s + tt * 64))[c]);
        }
#pragma unroll
        for (int tt = 0; tt < L; ++tt) gi_all[tt * 192 + k] = gi[tt];
    }
    __syncthreads();

    for (int tt = 0; tt < L; ++tt) {
        if (k < 192) {
            const float4* hv = (const float4*)h_s;
            float a0 = 0, a1 = 0, a2 = 0, a3 = 0;
#pragma unroll
            for (int c = 0; c < 16; c += 4) {
                a0 += dot4(whh4[c],     hv[c]);
                a1 += dot4(whh4[c + 1], hv[c + 1]);
                a2 += dot4(whh4[c + 2], hv[c + 2]);
                a3 += dot4(whh4[c + 3], hv[c + 3]);
            }
            gh_s[k] = (a0 + a1) + (a2 + a3) + bh;
        }
        __syncthreads();
        if (k < H) {
            float r = sigmoidf_(gi_all[tt * 192 + k] + gh_s[k]);
            float z = sigmoidf_(gi_all[tt * 192 + 64 + k] + gh_s[64 + k]);
            float n = tanhf(gi_all[tt * 192 + 128 + k] + r * gh_s[128 + k]);
            h_s[k] = (1.0f - z) * n + z * h_s[k];
        }
        __syncthreads();
    }

    if (k < H) g_out[k] = h_s[k];
}

// ---------------------------------------------------------------------------
// Kernel 2: W1 matvec. PROLOGUE (redundant per block, bit-identical →
// deterministic): wa/wb = f1W^T g, u_i/v_i = obs_i . wa/wb, factored flat
// softmax (Z_ij = u_i + v_j + const; const cancels) → eus/ev in LDS.
// Replaces 20 us of single-CU cold reads with ~3 us of L2-parallel reads.
// STREAM: 512 blocks = 32 row-groups x 16 column-groups; 16 rows/block,
// xr[7] virtual-x built once; row-pair interleaved nontemporal loads.
// All prologue state in LDS — no big register arrays, no min-waves cap.
// ---------------------------------------------------------------------------
__global__ __launch_bounds__(256) void k_mv(
    const float* __restrict__ W1, const float* __restrict__ obs,
    const float* __restrict__ f1W, const float* __restrict__ g,
    float* __restrict__ partial)
{
    __shared__ __align__(16) float g_s[64];
    __shared__ __align__(16) float wa_s[D];
    __shared__ __align__(16) float wb_s[D];
    __shared__ __align__(16) float eus_s[N];
    __shared__ __align__(16) float ev_s[N];
    __shared__ float wred[4][4];
    __shared__ float red[16][4];

    const int t = threadIdx.x;
    const int wave = t >> 6, lane = t & 63;

    // ---- prologue: softmax factors from g (redundant, L2-served) ----
    if (t < 64) g_s[t] = g[t];
    __syncthreads();

    {
        float s = 0.0f;
#pragma unroll 8
        for (int kk = 0; kk < 64; ++kk) s += f1W[kk * 256 + t] * g_s[kk];
        if (t < D) wa_s[t] = s;
        else       wb_s[t - D] = s;
    }
    __syncthreads();

    float u = 0.0f, v = 0.0f;
    {
        const float4* rp = (const float4*)(obs + t * D);
#pragma unroll 8
        for (int c = 0; c < 32; ++c) {
            float4 o = rp[c];
            u += dot4(o, ((const float4*)wa_s)[c]);
            v += dot4(o, ((const float4*)wb_s)[c]);
        }
    }

    float um = u, vm = v;
#pragma unroll
    for (int off = 32; off > 0; off >>= 1) {
        um = fmaxf(um, __shfl_xor(um, off, 64));
        vm = fmaxf(vm, __shfl_xor(vm, off, 64));
    }
    if (lane == 0) { wred[0][wave] = um; wred[1][wave] = vm; }
    __syncthreads();
    const float mu = fmaxf(fmaxf(wred[0][0], wred[0][1]), fmaxf(wred[0][2], wred[0][3]));
    const float mv = fmaxf(fmaxf(wred[1][0], wred[1][1]), fmaxf(wred[1][2], wred[1][3]));

    const float eui = expf(u - mu), evi = expf(v - mv);
    float us = eui, vs = evi;
#pragma unroll
    for (int off = 32; off > 0; off >>= 1) {
        us += __shfl_xor(us, off, 64);
        vs += __shfl_xor(vs, off, 64);
    }
    if (lane == 0) { wred[2][wave] = us; wred[3][wave] = vs; }
    __syncthreads();
    const float Su = (wred[2][0] + wred[2][1]) + (wred[2][2] + wred[2][3]);
    const float Sv = (wred[3][0] + wred[3][1]) + (wred[3][2] + wred[3][3]);

    eus_s[t] = eui * (1.0f / (Su * Sv));
    ev_s[t]  = evi;
    __syncthreads();

    // ---- stream: 16 rows x column-group cg ----
    const int cg   = blockIdx.x & 15;
    const int rgrp = blockIdx.x >> 4;      // 0..31

    v4f xr[7];
    {
        const float4* obs4 = (const float4*)obs;
#pragma unroll
        for (int j = 0; j < 7; ++j) {
            int idx = t + j * 256;           // < 1792
            int s   = idx / SEG4;
            int c4  = idx - s * SEG4;
            int seg = cg * 16 + s;
            float4 o;
            if (c4 < 32)       o = obs4[seg * 32 + c4];
            else if (c4 < 48)  o = ((const float4*)g_s)[c4 - 32];
            else {
                float4 e = ((const float4*)ev_s)[c4 - 48];
                float m = eus_s[seg];
                o = make_float4(e.x * m, e.y * m, e.z * m, e.w * m);
            }
            xr[j] = (v4f){o.x, o.y, o.z, o.w};
        }
    }

    const v4f* w0 = (const v4f*)W1 + (size_t)(rgrp * 16) * (F3IN / 4)
                  + (size_t)cg * CG4 + t;
    float sums[16];
#pragma unroll
    for (int rp = 0; rp < 8; ++rp) {
        const v4f* wra = w0 + (size_t)(2 * rp) * (F3IN / 4);
        const v4f* wrb = wra + (F3IN / 4);
        float s0a = 0, s0b = 0, s1a = 0, s1b = 0;
#pragma unroll
        for (int j = 0; j < 7; ++j) {
            v4f wa = __builtin_nontemporal_load(wra + j * 256);
            v4f wb = __builtin_nontemporal_load(wrb + j * 256);
            float da = dotv(wa, xr[j]);
            float db = dotv(wb, xr[j]);
            if (j & 1) { s0b += da; s1b += db; }
            else       { s0a += da; s1a += db; }
        }
        sums[2 * rp]     = s0a + s0b;
        sums[2 * rp + 1] = s1a + s1b;
    }

    __syncthreads();
#pragma unroll
    for (int rr = 0; rr < 16; ++rr) {
        float s = sums[rr];
#pragma unroll
        for (int off = 32; off > 0; off >>= 1) s += __shfl_down(s, off, 64);
        if (lane == 0) red[rr][wave] = s;
    }
    __syncthreads();
    if (t < 16)
        partial[(rgrp * 16 + t) * 16 + cg] =
            red[t][0] + red[t][1] + red[t][2] + red[t][3];
}

// ---------------------------------------------------------------------------
// Kernel 3: h1 = relu(sum of 16 partials + b1); out = W2 @ h1 + b2. One block.
// ---------------------------------------------------------------------------
__global__ __launch_bounds__(512) void k_finish(
    const float* __restrict__ partial, const float* __restrict__ b1,
    const float* __restrict__ W2, const float* __restrict__ b2,
    float* __restrict__ out)
{
    __shared__ float h1s[512];
    const int r = threadIdx.x;
    {
        const float4* p4 = (const float4*)(partial + r * 16);
        float4 A = p4[0], B = p4[1], C = p4[2], E = p4[3];
        float s = (A.x + A.y + A.z + A.w) + (B.x + B.y + B.z + B.w)
                + (C.x + C.y + C.z + C.w) + (E.x + E.y + E.z + E.w);
        h1s[r] = fmaxf(s + b1[r], 0.0f);
    }
    __syncthreads();

    const int wave = r >> 6, lane = r & 63;
    for (int row = wave; row < 40; row += 8) {
        float s = 0.0f;
#pragma unroll
        for (int c = 0; c < 8; ++c)
            s += W2[row * 512 + lane + c * 64] * h1s[lane + c * 64];
#pragma unroll
        for (int off = 32; off > 0; off >>= 1) s += __shfl_down(s, off, 64);
        if (lane == 0) out[row] = s + b2[row];
    }
}

// ---------------------------------------------------------------------------
extern "C" void kernel_launch(void* const* d_in, const int* in_sizes, int n_in,
                              void* d_out, int out_size, void* d_ws, size_t ws_size,
                              hipStream_t stream)
{
    const float* obs       = (const float*)d_in[0];
    const int*   token_ids = (const int*)  d_in[1];
    const float* emb_table = (const float*)d_in[2];
    const float* Wih       = (const float*)d_in[3];
    const float* Whh       = (const float*)d_in[4];
    const float* bih       = (const float*)d_in[5];
    const float* bhh       = (const float*)d_in[6];
    const float* f1W       = (const float*)d_in[7];
    // d_in[8] = f1_b : cancels in the flat softmax (Z_ij = u_i + v_j + const)
    const float* W1        = (const float*)d_in[9];
    const float* b1        = (const float*)d_in[10];
    const float* W2        = (const float*)d_in[11];
    const float* b2        = (const float*)d_in[12];

    float* ws      = (float*)d_ws;
    float* g       = ws;            // 64
    float* partial = ws + 640;      // 512*16 = 8192
    float* out     = (float*)d_out;

    k_gru<<<1, 256, 0, stream>>>(token_ids, emb_table, Wih, Whh, bih, bhh, g);
    k_mv<<<512, 256, 0, stream>>>(W1, obs, f1W, g, partial);
    k_finish<<<1, 512, 0, stream>>>(partial, b1, W2, b2, out);
}

// Round 11
// 73.712 us; speedup vs baseline: 1.7708x; 1.1728x over previous
//
#include <hip/hip_runtime.h>
#include <math.h>

#define H    64
#define N    256
#define D    128
#define L    16
#define SEG4   112                 // float4 per 448-col segment
#define F3IN (N * 448)             // 114688 floats per W1 row
#define CG4   1792                 // float4 per column group (16 segments)

typedef float v4f __attribute__((ext_vector_type(4)));

__device__ __forceinline__ float dot4(float4 a, float4 b) {
    return a.x * b.x + a.y * b.y + a.z * b.z + a.w * b.w;
}
__device__ __forceinline__ float dotv(v4f a, v4f b) {
    return a[0] * b[0] + a[1] * b[1] + a[2] * b[2] + a[3] * b[3];
}
// native-rate gates: v_rcp_f32 (~1 ulp) + __expf (v_exp path). GRU inputs are
// O(0.1); error ~1e-6 vs threshold 5.3e-2.
__device__ __forceinline__ float frcp(float x) {
    float r; asm("v_rcp_f32 %0, %1" : "=v"(r) : "v"(x)); return r;
}
__device__ __forceinline__ float fsigmoid(float x) {
    return frcp(1.0f + __expf(-x));
}
__device__ __forceinline__ float ftanh(float x) {
    return 1.0f - 2.0f * frcp(1.0f + __expf(2.0f * x));
}

// ---------------------------------------------------------------------------
// Kernel 1: encoder, latency-optimized. Same math as round 6 (ref-exact
// factored softmax; Z_ij = u_i + v_j + const, const cancels), but:
//  - native exp/rcp gates in the serial GRU (was libm tanhf/expf + fdiv)
//  - u/v phase fully coalesced: 8 rows per float4 instruction, 32-lane
//    cooperative dot + shfl reduce (was 64-lane x 512B-stride scatter)
// ---------------------------------------------------------------------------
__global__ __launch_bounds__(256, 1) void k_enc(
    const int* __restrict__ token_ids, const float* __restrict__ emb_table,
    const float* __restrict__ Wih, const float* __restrict__ Whh,
    const float* __restrict__ bih, const float* __restrict__ bhh,
    const float* __restrict__ f1W, const float* __restrict__ obs,
    float* __restrict__ g_out, float* __restrict__ eus_out,
    float* __restrict__ ev_out)
{
    __shared__ float emb_s[L * H];
    __shared__ float gi_all[L * 192];
    __shared__ float h_s[H];
    __shared__ float gh_s[192];
    __shared__ float wa_s[D];
    __shared__ float wb_s[D];
    __shared__ float u_arr[N];
    __shared__ float v_arr[N];
    __shared__ float wred[4][4];

    const int k = threadIdx.x;
    const int wave = k >> 6, lane = k & 63;

    {
        int tok = token_ids[k >> 4];
        ((float4*)emb_s)[k] = ((const float4*)emb_table)[tok * 16 + (k & 15)];
    }
    if (k < H) h_s[k] = 0.0f;

    // Whh gate row in registers (reused 16x); biases
    float4 whh4[16];
    float bi = 0.0f, bh = 0.0f;
    if (k < 192) {
        const float4* wh = (const float4*)(Whh + k * H);
#pragma unroll
        for (int c = 0; c < 16; ++c) whh4[c] = wh[c];
        bi = bih[k]; bh = bhh[k];
    }

    // f1W column k preloaded early (consumed after GRU; latency hidden)
    float f1wreg[64];
#pragma unroll
    for (int kk = 0; kk < 64; ++kk) f1wreg[kk] = f1W[kk * 256 + k];

    __syncthreads();

    // hoist input-gate terms: gi_all[t][k] = bih[k] + Wih[k,:].emb[t]
    // (Wih read once, directly — no register cache needed)
    if (k < 192) {
        float gi[L];
#pragma unroll
        for (int tt = 0; tt < L; ++tt) gi[tt] = bi;
        const float4* wi = (const float4*)(Wih + k * H);
#pragma unroll
        for (int c = 0; c < 16; ++c) {
            float4 w = wi[c];
#pragma unroll
            for (int tt = 0; tt < L; ++tt)
                gi[tt] += dot4(w, ((const float4*)(emb_s + tt * 64))[c]);
        }
#pragma unroll
        for (int tt = 0; tt < L; ++tt) gi_all[tt * 192 + k] = gi[tt];
    }
    __syncthreads();

    // serial GRU, 2 barriers per step, native-rate gates
    for (int tt = 0; tt < L; ++tt) {
        if (k < 192) {
            const float4* hv = (const float4*)h_s;
            float a0 = 0, a1 = 0, a2 = 0, a3 = 0;
#pragma unroll
            for (int c = 0; c < 16; c += 4) {
                a0 += dot4(whh4[c],     hv[c]);
                a1 += dot4(whh4[c + 1], hv[c + 1]);
                a2 += dot4(whh4[c + 2], hv[c + 2]);
                a3 += dot4(whh4[c + 3], hv[c + 3]);
            }
            gh_s[k] = (a0 + a1) + (a2 + a3) + bh;
        }
        __syncthreads();
        if (k < H) {
            float r = fsigmoid(gi_all[tt * 192 + k] + gh_s[k]);
            float z = fsigmoid(gi_all[tt * 192 + 64 + k] + gh_s[64 + k]);
            float n = ftanh(gi_all[tt * 192 + 128 + k] + r * gh_s[128 + k]);
            h_s[k] = (1.0f - z) * n + z * h_s[k];
        }
        __syncthreads();
    }

    // wa = f1W[:, :128]^T g ; wb = f1W[:, 128:]^T g
    {
        float s = 0.0f;
#pragma unroll
        for (int kk = 0; kk < 64; ++kk) s += f1wreg[kk] * h_s[kk];
        if (k < D) wa_s[k] = s;
        else       wb_s[k - D] = s;
        if (k < H) g_out[k] = h_s[k];
    }
    __syncthreads();

    // u_i = obs_i.wa, v_i = obs_i.wb — cooperative: 32-lane group per row,
    // 8 rows per instruction, fully coalesced 512B runs.
    {
        const float4* obs4 = (const float4*)obs;
        const float4* wa4  = (const float4*)wa_s;
        const float4* wb4  = (const float4*)wb_s;
        const int grp = k >> 5, cl = k & 31;
        float4 wav = wa4[cl], wbv = wb4[cl];
#pragma unroll 4
        for (int it = 0; it < 32; ++it) {
            int row = it * 8 + grp;
            float4 o = obs4[row * 32 + cl];
            float pu = dot4(o, wav);
            float pv = dot4(o, wbv);
#pragma unroll
            for (int off = 16; off > 0; off >>= 1) {
                pu += __shfl_down(pu, off, 32);
                pv += __shfl_down(pv, off, 32);
            }
            if (cl == 0) { u_arr[row] = pu; v_arr[row] = pv; }
        }
    }
    __syncthreads();

    const float u = u_arr[k], v = v_arr[k];

    float um = u, vm = v;
#pragma unroll
    for (int off = 32; off > 0; off >>= 1) {
        um = fmaxf(um, __shfl_xor(um, off, 64));
        vm = fmaxf(vm, __shfl_xor(vm, off, 64));
    }
    if (lane == 0) { wred[0][wave] = um; wred[1][wave] = vm; }
    __syncthreads();
    const float mu = fmaxf(fmaxf(wred[0][0], wred[0][1]), fmaxf(wred[0][2], wred[0][3]));
    const float mv = fmaxf(fmaxf(wred[1][0], wred[1][1]), fmaxf(wred[1][2], wred[1][3]));

    const float eui = expf(u - mu), evi = expf(v - mv);
    float us = eui, vs = evi;
#pragma unroll
    for (int off = 32; off > 0; off >>= 1) {
        us += __shfl_xor(us, off, 64);
        vs += __shfl_xor(vs, off, 64);
    }
    if (lane == 0) { wred[2][wave] = us; wred[3][wave] = vs; }
    __syncthreads();
    const float Su = (wred[2][0] + wred[2][1]) + (wred[2][2] + wred[2][3]);
    const float Sv = (wred[3][0] + wred[3][1]) + (wred[3][2] + wred[3][3]);

    eus_out[k] = eui * (1.0f / (Su * Sv));
    ev_out[k]  = evi;
}

// ---------------------------------------------------------------------------
// Kernel 2: W1 matvec with virtual x — EXACT round-6 (71.9us) version.
// ---------------------------------------------------------------------------
__global__ __launch_bounds__(256, 4) void k_mv(
    const float* __restrict__ W1, const float* __restrict__ obs,
    const float* __restrict__ g, const float* __restrict__ eus,
    const float* __restrict__ ev, float* __restrict__ partial)
{
    const int t  = threadIdx.x;
    const int cg = blockIdx.x & 15;
    const int rg = blockIdx.x >> 4;        // 0..255

    v4f xr[7];
    {
        const float4* obs4 = (const float4*)obs;
        const float4* g4   = (const float4*)g;
        const float4* ev4  = (const float4*)ev;
#pragma unroll
        for (int j = 0; j < 7; ++j) {
            int idx = t + j * 256;           // < 1792
            int s   = idx / SEG4;
            int c   = idx - s * SEG4;
            int seg = cg * 16 + s;
            float4 o;
            if (c < 32)       o = obs4[seg * 32 + c];
            else if (c < 48)  o = g4[c - 32];
            else {
                float4 e = ev4[c - 48];
                float m = eus[seg];
                o = make_float4(e.x * m, e.y * m, e.z * m, e.w * m);
            }
            xr[j] = (v4f){o.x, o.y, o.z, o.w};
        }
    }

    const v4f* w0 = (const v4f*)W1 + (size_t)(rg * 2) * (F3IN / 4)
                  + (size_t)cg * CG4 + t;
    const v4f* w1 = w0 + (F3IN / 4);

    float s0a = 0.0f, s0b = 0.0f, s1a = 0.0f, s1b = 0.0f;
#pragma unroll
    for (int j = 0; j < 7; ++j) {
        v4f wa = __builtin_nontemporal_load(w0 + j * 256);
        v4f wb = __builtin_nontemporal_load(w1 + j * 256);
        float da = dotv(wa, xr[j]);
        float db = dotv(wb, xr[j]);
        if (j & 1) { s0b += da; s1b += db; }
        else       { s0a += da; s1a += db; }
    }
    float sums[2] = { s0a + s0b, s1a + s1b };

    __shared__ float red[2][4];
    const int wave = t >> 6, lane = t & 63;
#pragma unroll
    for (int rr = 0; rr < 2; ++rr) {
        float s = sums[rr];
#pragma unroll
        for (int off = 32; off > 0; off >>= 1) s += __shfl_down(s, off, 64);
        if (lane == 0) red[rr][wave] = s;
    }
    __syncthreads();
    if (t < 2)
        partial[(rg * 2 + t) * 16 + cg] =
            red[t][0] + red[t][1] + red[t][2] + red[t][3];
}

// ---------------------------------------------------------------------------
// Kernel 3: finish — EXACT round-6 version.
// ---------------------------------------------------------------------------
__global__ __launch_bounds__(512) void k_finish(
    const float* __restrict__ partial, const float* __restrict__ b1,
    const float* __restrict__ W2, const float* __restrict__ b2,
    float* __restrict__ out)
{
    __shared__ float h1s[512];
    const int r = threadIdx.x;
    {
        const float4* p4 = (const float4*)(partial + r * 16);
        float4 A = p4[0], B = p4[1], C = p4[2], E = p4[3];
        float s = (A.x + A.y + A.z + A.w) + (B.x + B.y + B.z + B.w)
                + (C.x + C.y + C.z + C.w) + (E.x + E.y + E.z + E.w);
        h1s[r] = fmaxf(s + b1[r], 0.0f);
    }
    __syncthreads();

    const int wave = r >> 6, lane = r & 63;
    for (int row = wave; row < 40; row += 8) {
        float s = 0.0f;
#pragma unroll
        for (int c = 0; c < 8; ++c)
            s += W2[row * 512 + lane + c * 64] * h1s[lane + c * 64];
#pragma unroll
        for (int off = 32; off > 0; off >>= 1) s += __shfl_down(s, off, 64);
        if (lane == 0) out[row] = s + b2[row];
    }
}

// ---------------------------------------------------------------------------
extern "C" void kernel_launch(void* const* d_in, const int* in_sizes, int n_in,
                              void* d_out, int out_size, void* d_ws, size_t ws_size,
                              hipStream_t stream)
{
    const float* obs       = (const float*)d_in[0];
    const int*   token_ids = (const int*)  d_in[1];
    const float* emb_table = (const float*)d_in[2];
    const float* Wih       = (const float*)d_in[3];
    const float* Whh       = (const float*)d_in[4];
    const float* bih       = (const float*)d_in[5];
    const float* bhh       = (const float*)d_in[6];
    const float* f1W       = (const float*)d_in[7];
    // d_in[8] = f1_b : cancels in the flat softmax (Z_ij = u_i + v_j + const)
    const float* W1        = (const float*)d_in[9];
    const float* b1        = (const float*)d_in[10];
    const float* W2        = (const float*)d_in[11];
    const float* b2        = (const float*)d_in[12];

    float* ws      = (float*)d_ws;
    float* g       = ws;            // 64
    float* eus     = ws + 64;       // 256
    float* ev      = ws + 320;      // 256
    float* partial = ws + 640;      // 512*16 = 8192
    float* out     = (float*)d_out;

    k_enc<<<1, 256, 0, stream>>>(token_ids, emb_table, Wih, Whh, bih, bhh,
                                 f1W, obs, g, eus, ev);
    k_mv<<<4096, 256, 0, stream>>>(W1, obs, g, eus, ev, partial);
    k_finish<<<1, 512, 0, stream>>>(partial, b1, W2, b2, out);
}